// Round 14
// baseline (31.603 us; speedup 1.0000x reference)
//
#include <hip/hip_runtime.h>
#include <math.h>

typedef short bf16x8 __attribute__((ext_vector_type(8)));
typedef float f32x16 __attribute__((ext_vector_type(16)));
typedef unsigned int u32x4 __attribute__((ext_vector_type(4)));

#define B 16
#define N 4096
#define K 4096
#define OBJ_ELEMS (8*512*3)        // 12288 per batch
#define OBJ_VEC4  (OBJ_ELEMS/4)    // 3072 float4 per batch
#define NSEG 32
#define NCHUNK (N/NSEG)            // 128 adv rows per block (4 groups x 32)
#define BLK 512                    // 8 waves: 4 row-groups x 2 K-halves
#define NBLOCKS (NSEG*B)           // 512 blocks total
#define OBJ_V4_PER_BLK (OBJ_VEC4/NSEG) // 96 float4 per block
#define CD_W 0.2f
#define EPS_F 1e-7f

// ws layout (floats): csum[512] @0, lsq[512] @512, cnt(int) @1024
#define CS_OFF 0
#define LS_OFF NBLOCKS
#define CNT_OFF (2*NBLOCKS)

__device__ __forceinline__ unsigned short f2bf(float f) {
    unsigned int u = __float_as_uint(f);
    u = (u + 0x7FFFu + ((u >> 16) & 1u)) >> 16;   // RNE
    return (unsigned short)u;
}

__global__ __launch_bounds__(BLK) void chamfer_fused_kernel(
    const float* __restrict__ adv, const float* __restrict__ ori,
    const float* __restrict__ adv_obj, const float* __restrict__ ori_obj,
    const float* __restrict__ w,
    float* __restrict__ csum, float* __restrict__ lsq, int* __restrict__ cnt,
    float* __restrict__ out)
{
    __shared__ ushort4 slds[K];            // 32 KB: ori bf16 {-2x,-2y,-2z,o2}
    __shared__ float   rowmin[8][32];      // per-wave row-mins
    __shared__ float   a2lds[NCHUNK];      // fp32 |a|^2 per row
    __shared__ float   red_c[2], red_l[2];
    __shared__ int     lastflag;
    __shared__ float   sc[B], sl[B];

    const int nseg = blockIdx.x;
    const int b    = blockIdx.y;
    const int tid  = threadIdx.x;
    const int wid  = tid >> 6;
    const int lane = tid & 63;
    const int col  = lane & 31;
    const int hi   = lane >> 5;
    const int rg   = wid & 3;              // row group (32 rows each)
    const int kh   = wid >> 2;             // K half (2048 ori points each)

    // --- stage + convert ori into LDS (8 points per thread, coalesced) ---
    #pragma unroll
    for (int i = 0; i < K/BLK; ++i) {
        int p = tid + i*BLK;
        const float* s = ori + (b*K + p)*3;
        float x = s[0], y = s[1], z = s[2];
        float o2 = x*x + y*y + z*z;
        ushort4 u;
        u.x = f2bf(-2.f*x); u.y = f2bf(-2.f*y);
        u.z = f2bf(-2.f*z); u.w = f2bf(o2);
        slds[p] = u;
    }

    // --- A fragment: this wave's 32 adv rows, K=4 in low half ---
    const int n = nseg*NCHUNK + rg*32 + col;
    const float* ap = adv + (b*N + n)*3;
    float ax = ap[0], ay = ap[1], az = ap[2];
    float a2 = ax*ax + ay*ay + az*az;
    if (kh == 0 && hi == 0) a2lds[rg*32 + col] = a2;
    bf16x8 afrag;
    if (hi == 0) {
        afrag[0] = (short)f2bf(ax);
        afrag[1] = (short)f2bf(ay);
        afrag[2] = (short)f2bf(az);
        afrag[3] = (short)0x3F80;          // bf16 1.0
    } else {
        afrag[0] = 0; afrag[1] = 0; afrag[2] = 0; afrag[3] = 0;
    }
    afrag[4] = 0; afrag[5] = 0; afrag[6] = 0; afrag[7] = 0;

    __syncthreads();

    // --- main loop: this wave's K half as 32 paired-tile iterations ---
    // permutation-invariance of min lets lane col take points 2*(it*32+col)
    // and 2*(it*32+col)+1 from one ds_read_b128
    f32x16 acc = {INFINITY,INFINITY,INFINITY,INFINITY,
                  INFINITY,INFINITY,INFINITY,INFINITY,
                  INFINITY,INFINITY,INFINITY,INFINITY,
                  INFINITY,INFINITY,INFINITY,INFINITY};
    const f32x16 zc = {0,0,0,0, 0,0,0,0, 0,0,0,0, 0,0,0,0};
    const float4* s4 = reinterpret_cast<const float4*>(slds);  // 2 pts/float4

    #pragma unroll 4
    for (int it = kh*32; it < kh*32 + 32; ++it) {
        float4 q = s4[it*32 + col];
        u32x4 uu = __builtin_bit_cast(u32x4, q);
        u32x4 w0 = {uu.x, uu.y, 0u, 0u};
        u32x4 w1 = {uu.z, uu.w, 0u, 0u};
        bf16x8 b0 = __builtin_bit_cast(bf16x8, w0);
        bf16x8 b1 = __builtin_bit_cast(bf16x8, w1);
        f32x16 c0 = __builtin_amdgcn_mfma_f32_32x32x16_bf16(afrag, b0, zc, 0,0,0);
        f32x16 c1 = __builtin_amdgcn_mfma_f32_32x32x16_bf16(afrag, b1, zc, 0,0,0);
        #pragma unroll
        for (int r = 0; r < 16; ++r)
            acc[r] = fminf(fminf(c0[r], c1[r]), acc[r]);   // v_min3_f32
    }

    // --- col-min (over ori dim) within each 32-lane half ---
    #pragma unroll
    for (int r = 0; r < 16; ++r) {
        float v = acc[r];
        v = fminf(v, __shfl_xor(v, 1));
        v = fminf(v, __shfl_xor(v, 2));
        v = fminf(v, __shfl_xor(v, 4));
        v = fminf(v, __shfl_xor(v, 8));
        v = fminf(v, __shfl_xor(v, 16));
        acc[r] = v;
    }
    if (col == 0) {   // lanes 0 and 32 publish 16 rows each
        #pragma unroll
        for (int r = 0; r < 16; ++r)
            rowmin[wid][(r&3) + 8*(r>>2) + 4*hi] = acc[r];
    }
    __syncthreads();

    // --- epilogue: combine K-halves, add a2; waves 2-3 fold obj-L2 ---
    float s = 0.f;
    if (wid < 2) {             // 128 threads: one adv row each
        int row = tid;         // 0..127
        int rg2 = row >> 5, ri = row & 31;
        float m = fminf(rowmin[rg2][ri], rowmin[4 + rg2][ri]);
        s = m + a2lds[row];
    } else if (wid < 4) {      // 96 of 128 threads: obj-L2 slice
        int li = (wid - 2)*64 + lane;
        if (li < OBJ_V4_PER_BLK) {
            int idx = b*OBJ_VEC4 + nseg*OBJ_V4_PER_BLK + li;
            float4 a = reinterpret_cast<const float4*>(adv_obj)[idx];
            float4 o = reinterpret_cast<const float4*>(ori_obj)[idx];
            float dx = a.x - o.x, dy = a.y - o.y, dz = a.z - o.z, dw = a.w - o.w;
            s = dx*dx + dy*dy + dz*dz + dw*dw;
        }
    }
    #pragma unroll
    for (int off = 32; off; off >>= 1) s += __shfl_down(s, off);
    if (lane == 0) {
        if (wid < 2)       red_c[wid]     = s;
        else if (wid < 4)  red_l[wid - 2] = s;
    }
    __syncthreads();

    // --- publish partial + last-block detection (single thread) ---
    if (tid == 0) {
        csum[b*NSEG + nseg] = red_c[0] + red_c[1];
        lsq [b*NSEG + nseg] = red_l[0] + red_l[1];
        __threadfence();                       // release partials
        int old = atomicAdd(cnt, 1);
        lastflag = (old == NBLOCKS - 1);
    }
    __syncthreads();
    if (!lastflag) return;                     // block-uniform exit

    // --- last block: reduce all 512 partials + weights -> scalar out ---
    __threadfence();                           // acquire all partials
    {
        float c = csum[tid];                   // tid = bb*32 + seg
        float l = lsq [tid];
        #pragma unroll
        for (int off = 16; off; off >>= 1) {
            c += __shfl_down(c, off, 32);
            l += __shfl_down(l, off, 32);
        }
        int bb = tid >> 5;
        if ((tid & 31) == 0) { sc[bb] = c; sl[bb] = l; }
    }
    __syncthreads();
    if (tid < 64) {
        float cc = 0.f, ll = 0.f;
        if (tid < B) {
            float wt = w[tid];
            cc = (sc[tid] / (float)N) * wt;
            ll = sqrtf(sl[tid] + EPS_F) * wt;
        }
        #pragma unroll
        for (int off = 8; off; off >>= 1) {
            cc += __shfl_down(cc, off);
            ll += __shfl_down(ll, off);
        }
        if (tid == 0) out[0] = ll / (float)B + CD_W * (cc / (float)B);
    }
}

extern "C" void kernel_launch(void* const* d_in, const int* in_sizes, int n_in,
                              void* d_out, int out_size, void* d_ws, size_t ws_size,
                              hipStream_t stream)
{
    const float* adv_pc  = (const float*)d_in[0];
    const float* ori_pc  = (const float*)d_in[1];
    const float* adv_obj = (const float*)d_in[2];
    const float* ori_obj = (const float*)d_in[3];
    const float* weights = (const float*)d_in[4];
    float* out = (float*)d_out;
    float* ws  = (float*)d_ws;

    float* csum = ws + CS_OFF;
    float* lsq  = ws + LS_OFF;
    int*   cnt  = (int*)(ws + CNT_OFF);

    // reset completion counter (graph-capturable memset node)
    hipMemsetAsync(cnt, 0, sizeof(int), stream);

    // single fused kernel: MFMA chamfer + obj-L2 + last-block final combine
    chamfer_fused_kernel<<<dim3(NSEG, B), dim3(BLK), 0, stream>>>(
        adv_pc, ori_pc, adv_obj, ori_obj, weights, csum, lsq, cnt, out);
}

// Round 15
// 19.782 us; speedup vs baseline: 1.5976x; 1.5976x over previous
//
#include <hip/hip_runtime.h>
#include <math.h>

typedef short bf16x8 __attribute__((ext_vector_type(8)));
typedef float f32x16 __attribute__((ext_vector_type(16)));
typedef unsigned int u32x4 __attribute__((ext_vector_type(4)));

#define B 16
#define N 4096
#define K 4096
#define OBJ_ELEMS (8*512*3)        // 12288 per batch
#define OBJ_VEC4  (OBJ_ELEMS/4)    // 3072 float4 per batch
#define NSEG 32
#define NCHUNK (N/NSEG)            // 128 adv rows per block (4 groups x 32)
#define BLK 512                    // 8 waves: 4 row-groups x 2 K-halves
#define OBJ_V4_PER_BLK (OBJ_VEC4/NSEG) // 96 float4 per block
#define CD_W 0.2f
#define EPS_F 1e-7f

// ws layout (floats): csum[B*NSEG] @0, lsq[B*NSEG] @512
#define CS_OFF 0
#define LS_OFF (B*NSEG)

__device__ __forceinline__ unsigned int cvt_pk_bf16(float lo, float hi) {
    unsigned int r;
    asm volatile("v_cvt_pk_bf16_f32 %0, %1, %2" : "=v"(r) : "v"(lo), "v"(hi));
    return r;
}

__global__ __launch_bounds__(BLK) void chamfer_mfma_kernel(
    const float* __restrict__ adv, const float* __restrict__ ori,
    const float* __restrict__ adv_obj, const float* __restrict__ ori_obj,
    float* __restrict__ csum, float* __restrict__ lsq)
{
    __shared__ uint2 slds[K];              // 32 KB: ori bf16 {-2x,-2y | -2z,o2}
    __shared__ float rowmin[8][32];        // per-wave row-mins
    __shared__ float a2lds[NCHUNK];        // fp32 |a|^2 per row
    __shared__ float red_c[2], red_l[2];

    const int nseg = blockIdx.x;
    const int b    = blockIdx.y;
    const int tid  = threadIdx.x;
    const int wid  = tid >> 6;
    const int lane = tid & 63;
    const int col  = lane & 31;
    const int hi   = lane >> 5;
    const int rg   = wid & 3;              // row group (32 rows each)
    const int kh   = wid >> 2;             // K half (2048 ori points each)

    // --- stage + convert ori: 6 float4 loads -> 8 packed points per thread ---
    {
        const float4* src =
            reinterpret_cast<const float4*>(ori + (size_t)(b*K + tid*8)*3);
        float4 f0 = src[0], f1 = src[1], f2 = src[2];
        float4 f3 = src[3], f4 = src[4], f5 = src[5];
        float xs[8], ys[8], zs[8];
        xs[0]=f0.x; ys[0]=f0.y; zs[0]=f0.z;
        xs[1]=f0.w; ys[1]=f1.x; zs[1]=f1.y;
        xs[2]=f1.z; ys[2]=f1.w; zs[2]=f2.x;
        xs[3]=f2.y; ys[3]=f2.z; zs[3]=f2.w;
        xs[4]=f3.x; ys[4]=f3.y; zs[4]=f3.z;
        xs[5]=f3.w; ys[5]=f4.x; zs[5]=f4.y;
        xs[6]=f4.z; ys[6]=f4.w; zs[6]=f5.x;
        xs[7]=f5.y; ys[7]=f5.z; zs[7]=f5.w;
        #pragma unroll
        for (int j = 0; j < 8; ++j) {
            float x = xs[j], y = ys[j], z = zs[j];
            float o2 = x*x + y*y + z*z;
            uint2 e;
            e.x = cvt_pk_bf16(-2.f*x, -2.f*y);
            e.y = cvt_pk_bf16(-2.f*z, o2);
            slds[tid*8 + j] = e;
        }
    }

    // --- A fragment: this wave's 32 adv rows, K=4 in low half ---
    const int n = nseg*NCHUNK + rg*32 + col;
    const float* ap = adv + (b*N + n)*3;
    float ax = ap[0], ay = ap[1], az = ap[2];
    float a2 = ax*ax + ay*ay + az*az;
    if (kh == 0 && hi == 0) a2lds[rg*32 + col] = a2;
    unsigned int a01 = 0u, a23 = 0u;
    if (hi == 0) {
        a01 = cvt_pk_bf16(ax, ay);
        a23 = cvt_pk_bf16(az, 1.0f);
    }
    u32x4 aw = {a01, a23, 0u, 0u};
    bf16x8 afrag = __builtin_bit_cast(bf16x8, aw);

    __syncthreads();

    // --- main loop: this wave's 64 ori tiles of 32 points (half of K) ---
    f32x16 acc = {INFINITY,INFINITY,INFINITY,INFINITY,
                  INFINITY,INFINITY,INFINITY,INFINITY,
                  INFINITY,INFINITY,INFINITY,INFINITY,
                  INFINITY,INFINITY,INFINITY,INFINITY};
    const f32x16 zc = {0,0,0,0, 0,0,0,0, 0,0,0,0, 0,0,0,0};

    #pragma unroll 4
    for (int t = kh*64; t < kh*64 + 64; t += 2) {
        uint2 q0 = slds[t*32 + col];
        uint2 q1 = slds[(t+1)*32 + col];
        u32x4 w0 = {q0.x, q0.y, 0u, 0u};
        u32x4 w1 = {q1.x, q1.y, 0u, 0u};
        bf16x8 b0 = __builtin_bit_cast(bf16x8, w0);
        bf16x8 b1 = __builtin_bit_cast(bf16x8, w1);
        f32x16 c0 = __builtin_amdgcn_mfma_f32_32x32x16_bf16(afrag, b0, zc, 0,0,0);
        f32x16 c1 = __builtin_amdgcn_mfma_f32_32x32x16_bf16(afrag, b1, zc, 0,0,0);
        #pragma unroll
        for (int r = 0; r < 16; ++r)
            acc[r] = fminf(fminf(c0[r], c1[r]), acc[r]);   // v_min3_f32
    }

    // --- col-min (over ori dim) within each 32-lane half ---
    #pragma unroll
    for (int r = 0; r < 16; ++r) {
        float v = acc[r];
        v = fminf(v, __shfl_xor(v, 1));
        v = fminf(v, __shfl_xor(v, 2));
        v = fminf(v, __shfl_xor(v, 4));
        v = fminf(v, __shfl_xor(v, 8));
        v = fminf(v, __shfl_xor(v, 16));
        acc[r] = v;
    }
    if (col == 0) {   // lanes 0 and 32 publish 16 rows each
        #pragma unroll
        for (int r = 0; r < 16; ++r)
            rowmin[wid][(r&3) + 8*(r>>2) + 4*hi] = acc[r];
    }
    __syncthreads();

    // --- epilogue: combine K-halves, add a2; waves 2-3 fold obj-L2 ---
    float s = 0.f;
    if (wid < 2) {             // 128 threads: one adv row each
        int row = tid;         // 0..127
        int rg2 = row >> 5, ri = row & 31;
        float m = fminf(rowmin[rg2][ri], rowmin[4 + rg2][ri]);
        s = m + a2lds[row];
    } else if (wid < 4) {      // 96 of 128 threads: obj-L2 slice
        int li = (wid - 2)*64 + lane;
        if (li < OBJ_V4_PER_BLK) {
            int idx = b*OBJ_VEC4 + nseg*OBJ_V4_PER_BLK + li;
            float4 a = reinterpret_cast<const float4*>(adv_obj)[idx];
            float4 o = reinterpret_cast<const float4*>(ori_obj)[idx];
            float dx = a.x - o.x, dy = a.y - o.y, dz = a.z - o.z, dw = a.w - o.w;
            s = dx*dx + dy*dy + dz*dz + dw*dw;
        }
    }
    #pragma unroll
    for (int off = 32; off; off >>= 1) s += __shfl_down(s, off);
    if (lane == 0) {
        if (wid < 2)       red_c[wid]     = s;
        else if (wid < 4)  red_l[wid - 2] = s;
    }
    __syncthreads();
    if (tid == 0) csum[b*NSEG + nseg] = red_c[0] + red_c[1];
    if (tid == 1) lsq [b*NSEG + nseg] = red_l[0] + red_l[1];
}

__global__ __launch_bounds__(256) void final_kernel(
    const float* __restrict__ csum, const float* __restrict__ lsq,
    const float* __restrict__ w, float* __restrict__ out)
{
    const int tid = threadIdx.x;           // 256 threads, 2 partials each
    float c = csum[2*tid] + csum[2*tid + 1];
    float l = lsq [2*tid] + lsq [2*tid + 1];
    // 16 partial-pairs per batch live in one 16-lane group
    #pragma unroll
    for (int off = 8; off; off >>= 1) {
        c += __shfl_down(c, off, 16);
        l += __shfl_down(l, off, 16);
    }
    __shared__ float sc[B], sl[B];
    int bb = tid >> 4;
    if ((tid & 15) == 0) { sc[bb] = c; sl[bb] = l; }
    __syncthreads();
    if (tid < 64) {
        float cc = 0.f, ll = 0.f;
        if (tid < B) {
            float wt = w[tid];
            cc = (sc[tid] / (float)N) * wt;
            ll = sqrtf(sl[tid] + EPS_F) * wt;
        }
        #pragma unroll
        for (int off = 8; off; off >>= 1) {
            cc += __shfl_down(cc, off);
            ll += __shfl_down(ll, off);
        }
        if (tid == 0) out[0] = ll / (float)B + CD_W * (cc / (float)B);
    }
}

extern "C" void kernel_launch(void* const* d_in, const int* in_sizes, int n_in,
                              void* d_out, int out_size, void* d_ws, size_t ws_size,
                              hipStream_t stream)
{
    const float* adv_pc  = (const float*)d_in[0];
    const float* ori_pc  = (const float*)d_in[1];
    const float* adv_obj = (const float*)d_in[2];
    const float* ori_obj = (const float*)d_in[3];
    const float* weights = (const float*)d_in[4];
    float* out = (float*)d_out;
    float* ws  = (float*)d_ws;

    float* csum = ws + CS_OFF;
    float* lsq  = ws + LS_OFF;

    // 1) fused MFMA chamfer (in-block K-split, 8 waves) + obj-L2 partials:
    //    grid = (NSEG, B) = 512 blocks of 512
    chamfer_mfma_kernel<<<dim3(NSEG, B), dim3(BLK), 0, stream>>>(
        adv_pc, ori_pc, adv_obj, ori_obj, csum, lsq);

    // 2) weighted final combine (1 block)
    final_kernel<<<dim3(1), dim3(256), 0, stream>>>(csum, lsq, weights, out);
}

// Round 16
// 19.595 us; speedup vs baseline: 1.6128x; 1.0095x over previous
//
#include <hip/hip_runtime.h>
#include <math.h>

typedef short bf16x8 __attribute__((ext_vector_type(8)));
typedef float f32x16 __attribute__((ext_vector_type(16)));
typedef unsigned int u32x4 __attribute__((ext_vector_type(4)));

#define B 16
#define N 4096
#define K 4096
#define OBJ_ELEMS (8*512*3)        // 12288 per batch
#define OBJ_VEC4  (OBJ_ELEMS/4)    // 3072 float4 per batch
#define NSEG 32
#define NCHUNK (N/NSEG)            // 128 adv rows per block (4 groups x 32)
#define BLK 512                    // 8 waves: 4 row-groups x 2 K-halves
#define OBJ_V4_PER_BLK (OBJ_VEC4/NSEG) // 96 float4 per block
#define CD_W 0.2f
#define EPS_F 1e-7f

// ws layout (floats): csum[B*NSEG] @0, lsq[B*NSEG] @512
#define CS_OFF 0
#define LS_OFF (B*NSEG)

__device__ __forceinline__ unsigned int cvt_pk_bf16(float lo, float hi) {
    unsigned int r;
    asm volatile("v_cvt_pk_bf16_f32 %0, %1, %2" : "=v"(r) : "v"(lo), "v"(hi));
    return r;
}

__global__ __launch_bounds__(BLK, 4) void chamfer_mfma_kernel(
    const float* __restrict__ adv, const float* __restrict__ ori,
    const float* __restrict__ adv_obj, const float* __restrict__ ori_obj,
    float* __restrict__ csum, float* __restrict__ lsq)
{
    __shared__ uint2 slds[K];              // 32 KB: ori bf16 {-2x,-2y | -2z,o2}
    __shared__ float rowmin[8][32];        // per-wave row-mins
    __shared__ float a2lds[NCHUNK];        // fp32 |a|^2 per row
    __shared__ float red_c[2], red_l[2];

    const int nseg = blockIdx.x;
    const int b    = blockIdx.y;
    const int tid  = threadIdx.x;
    const int wid  = tid >> 6;
    const int lane = tid & 63;
    const int col  = lane & 31;
    const int hi   = lane >> 5;
    const int rg   = wid & 3;              // row group (32 rows each)
    const int kh   = wid >> 2;             // K half (2048 ori points each)

    // --- stage + convert ori: 6 float4 loads -> 8 packed points per thread ---
    {
        const float4* src =
            reinterpret_cast<const float4*>(ori + (size_t)(b*K + tid*8)*3);
        float4 f0 = src[0], f1 = src[1], f2 = src[2];
        float4 f3 = src[3], f4 = src[4], f5 = src[5];
        float xs[8], ys[8], zs[8];
        xs[0]=f0.x; ys[0]=f0.y; zs[0]=f0.z;
        xs[1]=f0.w; ys[1]=f1.x; zs[1]=f1.y;
        xs[2]=f1.z; ys[2]=f1.w; zs[2]=f2.x;
        xs[3]=f2.y; ys[3]=f2.z; zs[3]=f2.w;
        xs[4]=f3.x; ys[4]=f3.y; zs[4]=f3.z;
        xs[5]=f3.w; ys[5]=f4.x; zs[5]=f4.y;
        xs[6]=f4.z; ys[6]=f4.w; zs[6]=f5.x;
        xs[7]=f5.y; ys[7]=f5.z; zs[7]=f5.w;
        #pragma unroll
        for (int j = 0; j < 8; ++j) {
            float x = xs[j], y = ys[j], z = zs[j];
            float o2 = x*x + y*y + z*z;
            uint2 e;
            e.x = cvt_pk_bf16(-2.f*x, -2.f*y);
            e.y = cvt_pk_bf16(-2.f*z, o2);
            slds[tid*8 + j] = e;
        }
    }

    // --- A fragment: this wave's 32 adv rows, K=4 in low half ---
    const int n = nseg*NCHUNK + rg*32 + col;
    const float* ap = adv + (b*N + n)*3;
    float ax = ap[0], ay = ap[1], az = ap[2];
    float a2 = ax*ax + ay*ay + az*az;
    if (kh == 0 && hi == 0) a2lds[rg*32 + col] = a2;
    unsigned int a01 = 0u, a23 = 0u;
    if (hi == 0) {
        a01 = cvt_pk_bf16(ax, ay);
        a23 = cvt_pk_bf16(az, 1.0f);
    }
    u32x4 aw = {a01, a23, 0u, 0u};
    bf16x8 afrag = __builtin_bit_cast(bf16x8, aw);

    __syncthreads();

    // --- main loop: 4 phases; each phase preloads 8 float4 (16 ori points)
    //     into registers, then runs 8 memory-free MFMA+min3 iterations ---
    f32x16 acc = {INFINITY,INFINITY,INFINITY,INFINITY,
                  INFINITY,INFINITY,INFINITY,INFINITY,
                  INFINITY,INFINITY,INFINITY,INFINITY,
                  INFINITY,INFINITY,INFINITY,INFINITY};
    const f32x16 zc = {0,0,0,0, 0,0,0,0, 0,0,0,0, 0,0,0,0};
    const float4* s4 = reinterpret_cast<const float4*>(slds);  // 2 pts/float4

    #pragma unroll
    for (int ph = 0; ph < 4; ++ph) {
        float4 f[8];
        #pragma unroll
        for (int j = 0; j < 8; ++j)
            f[j] = s4[(kh*32 + ph*8 + j)*32 + col];
        #pragma unroll
        for (int j = 0; j < 8; ++j) {
            u32x4 uu = __builtin_bit_cast(u32x4, f[j]);
            u32x4 w0 = {uu.x, uu.y, 0u, 0u};
            u32x4 w1 = {uu.z, uu.w, 0u, 0u};
            bf16x8 b0 = __builtin_bit_cast(bf16x8, w0);
            bf16x8 b1 = __builtin_bit_cast(bf16x8, w1);
            f32x16 c0 = __builtin_amdgcn_mfma_f32_32x32x16_bf16(afrag, b0, zc, 0,0,0);
            f32x16 c1 = __builtin_amdgcn_mfma_f32_32x32x16_bf16(afrag, b1, zc, 0,0,0);
            #pragma unroll
            for (int r = 0; r < 16; ++r)
                acc[r] = fminf(fminf(c0[r], c1[r]), acc[r]);   // v_min3_f32
        }
    }

    // --- col-min (over ori dim) within each 32-lane half ---
    #pragma unroll
    for (int r = 0; r < 16; ++r) {
        float v = acc[r];
        v = fminf(v, __shfl_xor(v, 1));
        v = fminf(v, __shfl_xor(v, 2));
        v = fminf(v, __shfl_xor(v, 4));
        v = fminf(v, __shfl_xor(v, 8));
        v = fminf(v, __shfl_xor(v, 16));
        acc[r] = v;
    }
    if (col == 0) {   // lanes 0 and 32 publish 16 rows each
        #pragma unroll
        for (int r = 0; r < 16; ++r)
            rowmin[wid][(r&3) + 8*(r>>2) + 4*hi] = acc[r];
    }
    __syncthreads();

    // --- epilogue: combine K-halves, add a2; waves 2-3 fold obj-L2 ---
    float s = 0.f;
    if (wid < 2) {             // 128 threads: one adv row each
        int row = tid;         // 0..127
        int rg2 = row >> 5, ri = row & 31;
        float m = fminf(rowmin[rg2][ri], rowmin[4 + rg2][ri]);
        s = m + a2lds[row];
    } else if (wid < 4) {      // 96 of 128 threads: obj-L2 slice
        int li = (wid - 2)*64 + lane;
        if (li < OBJ_V4_PER_BLK) {
            int idx = b*OBJ_VEC4 + nseg*OBJ_V4_PER_BLK + li;
            float4 a = reinterpret_cast<const float4*>(adv_obj)[idx];
            float4 o = reinterpret_cast<const float4*>(ori_obj)[idx];
            float dx = a.x - o.x, dy = a.y - o.y, dz = a.z - o.z, dw = a.w - o.w;
            s = dx*dx + dy*dy + dz*dz + dw*dw;
        }
    }
    #pragma unroll
    for (int off = 32; off; off >>= 1) s += __shfl_down(s, off);
    if (lane == 0) {
        if (wid < 2)       red_c[wid]     = s;
        else if (wid < 4)  red_l[wid - 2] = s;
    }
    __syncthreads();
    if (tid == 0) csum[b*NSEG + nseg] = red_c[0] + red_c[1];
    if (tid == 1) lsq [b*NSEG + nseg] = red_l[0] + red_l[1];
}

__global__ __launch_bounds__(256) void final_kernel(
    const float* __restrict__ csum, const float* __restrict__ lsq,
    const float* __restrict__ w, float* __restrict__ out)
{
    const int tid = threadIdx.x;           // 256 threads, 2 partials each
    float c = csum[2*tid] + csum[2*tid + 1];
    float l = lsq [2*tid] + lsq [2*tid + 1];
    // 16 partial-pairs per batch live in one 16-lane group
    #pragma unroll
    for (int off = 8; off; off >>= 1) {
        c += __shfl_down(c, off, 16);
        l += __shfl_down(l, off, 16);
    }
    __shared__ float sc[B], sl[B];
    int bb = tid >> 4;
    if ((tid & 15) == 0) { sc[bb] = c; sl[bb] = l; }
    __syncthreads();
    if (tid < 64) {
        float cc = 0.f, ll = 0.f;
        if (tid < B) {
            float wt = w[tid];
            cc = (sc[tid] / (float)N) * wt;
            ll = sqrtf(sl[tid] + EPS_F) * wt;
        }
        #pragma unroll
        for (int off = 8; off; off >>= 1) {
            cc += __shfl_down(cc, off);
            ll += __shfl_down(ll, off);
        }
        if (tid == 0) out[0] = ll / (float)B + CD_W * (cc / (float)B);
    }
}

extern "C" void kernel_launch(void* const* d_in, const int* in_sizes, int n_in,
                              void* d_out, int out_size, void* d_ws, size_t ws_size,
                              hipStream_t stream)
{
    const float* adv_pc  = (const float*)d_in[0];
    const float* ori_pc  = (const float*)d_in[1];
    const float* adv_obj = (const float*)d_in[2];
    const float* ori_obj = (const float*)d_in[3];
    const float* weights = (const float*)d_in[4];
    float* out = (float*)d_out;
    float* ws  = (float*)d_ws;

    float* csum = ws + CS_OFF;
    float* lsq  = ws + LS_OFF;

    // 1) fused MFMA chamfer (phase-register B-fragments, 8 waves):
    //    grid = (NSEG, B) = 512 blocks of 512
    chamfer_mfma_kernel<<<dim3(NSEG, B), dim3(BLK), 0, stream>>>(
        adv_pc, ori_pc, adv_obj, ori_obj, csum, lsq);

    // 2) weighted final combine (1 block)
    final_kernel<<<dim3(1), dim3(256), 0, stream>>>(csum, lsq, weights, out);
}